// Round 1
// 532.961 us; speedup vs baseline: 1.0498x; 1.0498x over previous
//
#include <hip/hip_runtime.h>

typedef unsigned short u16;
typedef __bf16 bf16x8 __attribute__((ext_vector_type(8)));
typedef float f32x4 __attribute__((ext_vector_type(4)));

__device__ __forceinline__ float b2f(u16 b){ union{unsigned u; float f;} v; v.u=((unsigned)b)<<16; return v.f; }
__device__ __forceinline__ u16 f2b(float f){ unsigned u=__builtin_bit_cast(unsigned,f); return (u16)((u+0x7fffu+((u>>16)&1u))>>16); }
__device__ __forceinline__ float wred(float v){
  #pragma unroll
  for(int off=32; off>0; off>>=1) v += __shfl_xor(v, off, 64);
  return v;
}
__device__ __forceinline__ void stOut(u16* p, float v){ *p = f2b(v); }
__device__ __forceinline__ void stOut(float* p, float v){ *p = v; }

// stage 8 contiguous elements into LDS as bf16; source may be bf16 (copy) or fp32 (convert)
__device__ __forceinline__ void stageA8(u16* dst, const u16* src){
  *(int4*)dst = *(const int4*)src;
}
__device__ __forceinline__ void stageA8(u16* dst, const float* src){
  float4 a = *(const float4*)src;
  float4 b = *(const float4*)(src+4);
  ushort4 o0; o0.x=f2b(a.x); o0.y=f2b(a.y); o0.z=f2b(a.z); o0.w=f2b(a.w);
  ushort4 o1; o1.x=f2b(b.x); o1.y=f2b(b.y); o1.z=f2b(b.z); o1.w=f2b(b.w);
  *(ushort4*)dst = o0;
  *(ushort4*)(dst+4) = o1;
}

// ---------------- generic MFMA GEMM: C[M,N] = act(A[M,K] @ Wt^T + bias) ----------------
// A bf16 or fp32 (converted during staging). Wt pre-transposed bf16: Wt[n][k], row stride K.
// Tiles BM=128, BN=64, BK=64.
// MODE 0: +bias. MODE 1: relu(+bias). MODE 2: mult*sigmoid(+bias).
// DUAL: K is split in half; first half of k reads A, second half reads A2 (both lda).
template<int MODE, typename OT, typename AT, bool DUAL>
__global__ __launch_bounds__(256) void gemm_k(
    const AT* __restrict__ A, const AT* __restrict__ A2, int lda,
    const u16* __restrict__ Wt, int K,
    const float* __restrict__ bias, int Nreal,
    OT* __restrict__ C, int ldc,
    const u16* __restrict__ mult, int ldm)
{
  const int LP = 72; // padded LDS row (bf16): 144B rows -> only 2-way bank alias (free)
  __shared__ __align__(16) u16 As[128*72];
  __shared__ __align__(16) u16 Bs[64*72];
  const int tid = threadIdx.x;
  const size_t m0 = (size_t)blockIdx.x * 128;
  const int n0 = blockIdx.y * 64;
  const int lane = tid & 63, w = tid >> 6;
  const int lr = lane & 15, quad = lane >> 4;
  const int wr = (w >> 1) * 64, wc = (w & 1) * 32;
  const int KH = K >> 1;

  f32x4 acc[4][2];
  #pragma unroll
  for(int i=0;i<4;++i)
    #pragma unroll
    for(int j=0;j<2;++j) acc[i][j] = (f32x4){0.f,0.f,0.f,0.f};

  for(int k0=0; k0<K; k0+=64){
    const AT* Ap = A;
    int kcol = k0;
    if (DUAL && k0 >= KH) { Ap = A2; kcol = k0 - KH; }
    #pragma unroll
    for(int it=0; it<4; ++it){            // A tile: 128x64 bf16 = 1024 x 8-elem chunks
      int ch = tid + 256*it; int r = ch>>3, s = (ch&7)*8;
      stageA8(&As[r*LP + s], Ap + (m0+r)*(size_t)lda + kcol + s);
    }
    #pragma unroll
    for(int it=0; it<2; ++it){            // W tile: 64x64
      int ch = tid + 256*it; int r = ch>>3, s = (ch&7)*8;
      *(int4*)&Bs[r*LP + s] = *(const int4*)&Wt[(size_t)(n0+r)*K + k0 + s];
    }
    __syncthreads();
    #pragma unroll
    for(int kk=0; kk<64; kk+=32){
      bf16x8 af[4], bfr[2];
      #pragma unroll
      for(int i=0;i<4;++i) af[i]  = *(const bf16x8*)&As[(wr + i*16 + lr)*LP + kk + quad*8];
      #pragma unroll
      for(int j=0;j<2;++j) bfr[j] = *(const bf16x8*)&Bs[(wc + j*16 + lr)*LP + kk + quad*8];
      #pragma unroll
      for(int i=0;i<4;++i)
        #pragma unroll
        for(int j=0;j<2;++j)
          acc[i][j] = __builtin_amdgcn_mfma_f32_16x16x32_bf16(af[i], bfr[j], acc[i][j], 0, 0, 0);
    }
    __syncthreads();
  }
  // epilogue: D row = wr+i*16+quad*4+r, col = wc+j*16+lr
  #pragma unroll
  for(int j=0;j<2;++j){
    int col = n0 + wc + j*16 + lr;
    float bv = (col < Nreal) ? bias[col] : 0.f;
    #pragma unroll
    for(int i=0;i<4;++i){
      #pragma unroll
      for(int r=0;r<4;++r){
        size_t row = m0 + wr + i*16 + quad*4 + r;
        size_t ci = row*(size_t)ldc + col;
        float v = acc[i][j][r] + bv;
        if(MODE==1) v = fmaxf(v, 0.f);
        if(MODE==2){ float mv = b2f(mult[row*(size_t)ldm + col]); v = mv / (1.f + __expf(-v)); }
        stOut(&C[ci], v);
      }
    }
  }
}

// ---------------- weight pre-transpose fp32->bf16 (+zero pad): dst[n*Kp+k] = src[k*N+n]
struct TPar { const float* src; u16* dst; int K, N, Kp, Np; };
struct TArgs { TPar p[8]; };
__global__ __launch_bounds__(256) void transpose_all(TArgs args){
  TPar p = args.p[blockIdx.y];
  int idx = blockIdx.x*256 + threadIdx.x;
  int total = p.Np * p.Kp;
  if (idx >= total) return;
  int n = idx / p.Kp, k = idx - n*p.Kp;
  u16 v = 0;
  if (n < p.N && k < p.K) v = f2b(p.src[(size_t)k*p.N + n]);
  p.dst[idx] = v;
}

// ---------------- row-wise middle (weighted aliases eb, common aliases ep; same-row in-place)
__global__ __launch_bounds__(256) void mid_k(
    const u16* eb, const u16* ef, const u16* ep,
    const float* __restrict__ Wg, const float* __restrict__ bg,
    u16* common, u16* weighted)
{
  const int wid = threadIdx.x >> 6, lane = threadIdx.x & 63;
  const size_t row = (size_t)blockIdx.x * 4 + wid;
  const size_t base = row*256 + lane*4;

  ushort4 vb = *(const ushort4*)(eb + base);
  ushort4 vf = *(const ushort4*)(ef + base);
  ushort4 vp = *(const ushort4*)(ep + base);
  float fb[4] = {b2f(vb.x), b2f(vb.y), b2f(vb.z), b2f(vb.w)};
  float ff[4] = {b2f(vf.x), b2f(vf.y), b2f(vf.z), b2f(vf.w)};
  float fp[4] = {b2f(vp.x), b2f(vp.y), b2f(vp.z), b2f(vp.w)};

  float sb=0, sf=0, sp=0, d01=0, d02=0, d12=0, g0=0, g1=0, g2=0;
  #pragma unroll
  for(int j=0;j<4;++j){
    sb += fb[j]*fb[j]; sf += ff[j]*ff[j]; sp += fp[j]*fp[j];
    d01 += fb[j]*ff[j]; d02 += fb[j]*fp[j]; d12 += ff[j]*fp[j];
  }
  // weight generator: allc @ Wg, Wg is [768,3] fp32 row-major
  #pragma unroll
  for(int seg=0; seg<3; ++seg){
    const float* x = (seg==0) ? fb : (seg==1) ? ff : fp;
    const float* wg = Wg + ((size_t)seg*256 + lane*4)*3;
    float4 w0 = *(const float4*)(wg);
    float4 w1 = *(const float4*)(wg+4);
    float4 w2 = *(const float4*)(wg+8);
    float wv[12] = {w0.x,w0.y,w0.z,w0.w, w1.x,w1.y,w1.z,w1.w, w2.x,w2.y,w2.z,w2.w};
    #pragma unroll
    for(int j=0;j<4;++j){
      g0 += x[j]*wv[j*3+0];
      g1 += x[j]*wv[j*3+1];
      g2 += x[j]*wv[j*3+2];
    }
  }
  sb=wred(sb); sf=wred(sf); sp=wred(sp);
  d01=wred(d01); d02=wred(d02); d12=wred(d12);
  g0=wred(g0); g1=wred(g1); g2=wred(g2);

  float nb = fmaxf(sqrtf(sb), 1e-12f);
  float nf = fmaxf(sqrtf(sf), 1e-12f);
  float np_ = fmaxf(sqrtf(sp), 1e-12f);
  float s01 = d01/(nb*nf), s02 = d02/(nb*np_), s12 = d12/(nf*np_);

  g0 += bg[0]; g1 += bg[1]; g2 += bg[2];
  float gm = fmaxf(g0, fmaxf(g1, g2));
  float e0 = expf(g0-gm), e1 = expf(g1-gm), e2 = expf(g2-gm);
  float es = e0+e1+e2;
  float fw0 = e0/es, fw1 = e1/es, fw2 = e2/es;

  bool p0 = s01 > 0.6f, p1 = s02 > 0.6f, p2 = s12 > 0.6f;
  bool has = p0 || p1 || p2;
  float mm = -__builtin_inff();
  if(p0) mm = fmaxf(mm, s01);
  if(p1) mm = fmaxf(mm, s02);
  if(p2) mm = fmaxf(mm, s12);
  if(!has) mm = 0.f;
  float q0 = p0 ? expf(s01-mm) : 0.f;
  float q1 = p1 ? expf(s02-mm) : 0.f;
  float q2 = p2 ? expf(s12-mm) : 0.f;
  float qs = fmaxf(q0+q1+q2, 1e-12f);
  float w0 = q0/qs, w1 = q1/qs, w2 = q2/qs;

  float inb = 1.f/nb, invf = 1.f/nf, inp = 1.f/np_;
  u16 co[4], wt[4];
  #pragma unroll
  for(int j=0;j<4;++j){
    float a = fb[j], b = ff[j], c = fp[j];
    float na = a*inb, nbv = b*invf, nc = c*inp;
    float c0 = (na*nbv > 0.6f) ? 0.5f*(a+b) : 0.f;
    float c1 = (na*nc  > 0.6f) ? 0.5f*(a+c) : 0.f;
    float c2 = (nbv*nc > 0.6f) ? 0.5f*(b+c) : 0.f;
    float sc = c0*w0 + c1*w1 + c2*w2;
    float cf = has ? sc : (a+b+c)*(1.f/3.f);
    float wv = a*fw0 + b*fw1 + c*fw2;
    co[j] = f2b(cf); wt[j] = f2b(wv);
  }
  ushort4 oc, ow;
  oc.x=co[0]; oc.y=co[1]; oc.z=co[2]; oc.w=co[3];
  ow.x=wt[0]; ow.y=wt[1]; ow.z=wt[2]; ow.w=wt[3];
  *(ushort4*)(common + base) = oc;     // in-place over ep
  *(ushort4*)(weighted + base) = ow;   // in-place over eb
}

extern "C" void kernel_launch(void* const* d_in, const int* in_sizes, int n_in,
                              void* d_out, int out_size, void* d_ws, size_t ws_size,
                              hipStream_t stream) {
  const float* brics = (const float*)d_in[0];
  const float* fg    = (const float*)d_in[1];
  const float* ph    = (const float*)d_in[2];
  const float* W1[3] = {(const float*)d_in[3], (const float*)d_in[7], (const float*)d_in[11]};
  const float* b1[3] = {(const float*)d_in[4], (const float*)d_in[8], (const float*)d_in[12]};
  const float* W2[3] = {(const float*)d_in[5], (const float*)d_in[9], (const float*)d_in[13]};
  const float* b2[3] = {(const float*)d_in[6], (const float*)d_in[10], (const float*)d_in[14]};
  const float* Wg = (const float*)d_in[15];
  const float* bg = (const float*)d_in[16];
  const float* We = (const float*)d_in[17];
  const float* be = (const float*)d_in[18];
  const float* Wf = (const float*)d_in[19];
  const float* bf = (const float*)d_in[20];
  float* out = (float*)d_out;

  const int M = in_sizes[0] / 256;   // 65536

  // ---- workspace carve ----
  char* wsp = (char*)d_ws;
  size_t off = 0;
  auto carve = [&](size_t elems)->u16* {
    u16* p = (u16*)(wsp + off);
    off += ((elems*sizeof(u16)) + 255) & ~(size_t)255;
    return p;
  };
  u16* xb0 = carve((size_t)M*256);   // enc0 (brics), then weighted (in-place)
  u16* xb1 = carve((size_t)M*256);   // enc1 (fg), then ce (gate out)
  u16* xb2 = carve((size_t)M*256);   // enc2 (ph), then common (in-place)
  u16* h   = carve((size_t)M*320);   // encoder hidden
  u16* Wt1[3], *Wt2[3];
  for(int i=0;i<3;++i) Wt1[i] = carve(320*256);
  for(int i=0;i<3;++i) Wt2[i] = carve(256*320);
  u16* WtE = carve(256*256);
  u16* WtF = carve(256*512);         // full fused-output weight: [n=256][k=512]
  (void)ws_size; (void)n_in; (void)out_size;

  // ---- 1. transpose/convert all weights (activation convert is fused into GEMM1 staging) ----
  TArgs ta;
  for(int i=0;i<3;++i){
    ta.p[i]   = {W1[i], Wt1[i], 256, 300, 256, 320};  // Wt1: [320][256]
    ta.p[3+i] = {W2[i], Wt2[i], 300, 256, 320, 256};  // Wt2: [256][320]
  }
  ta.p[6] = {We, WtE, 256, 256, 256, 256};
  ta.p[7] = {Wf, WtF, 512, 256, 512, 256};            // Wf: [512,256] -> WtF [256][512]
  transpose_all<<<dim3(512, 8), 256, 0, stream>>>(ta);

  // ---- 2. encoders: h = relu(x_fp32@W1+b1); enc[i] = h@W2+b2 ----
  const float* xin[3] = {brics, fg, ph};
  u16* encp[3] = {xb0, xb1, xb2};
  for(int i=0;i<3;++i){
    gemm_k<1,u16,float,false><<<dim3(M/128, 5), 256, 0, stream>>>(
        xin[i], nullptr, 256, Wt1[i], 256, b1[i], 300, h, 320, nullptr, 0);
    gemm_k<0,u16,u16,false><<<dim3(M/128, 4), 256, 0, stream>>>(
        h, nullptr, 320, Wt2[i], 320, b2[i], 256, encp[i], 256, nullptr, 0);
  }

  // ---- 3. row-wise middle: weighted -> xb0 (in place), common -> xb2 (in place) ----
  mid_k<<<M/4, 256, 0, stream>>>(xb0, xb1, xb2, Wg, bg, /*common=*/xb2, /*weighted=*/xb0);

  // ---- 4. gate: ce(xb1) = common * sigmoid(common@We + be) ----
  gemm_k<2,u16,u16,false><<<dim3(M/128, 4), 256, 0, stream>>>(
      xb2, nullptr, 256, WtE, 256, be, 256, xb1, 256, xb2, 256);

  // ---- 5. fused output: out = [weighted | ce] @ WtF^T + bf  (single K=512 GEMM) ----
  gemm_k<0,float,u16,true><<<dim3(M/128, 4), 256, 0, stream>>>(
      xb0, xb1, 256, WtF, 512, bf, 256, out, 256, nullptr, 0);
}

// Round 2
// 522.898 us; speedup vs baseline: 1.0700x; 1.0192x over previous
//
#include <hip/hip_runtime.h>

typedef unsigned short u16;
typedef __bf16 bf16x8 __attribute__((ext_vector_type(8)));
typedef float f32x4 __attribute__((ext_vector_type(4)));

__device__ __forceinline__ float b2f(u16 b){ union{unsigned u; float f;} v; v.u=((unsigned)b)<<16; return v.f; }
__device__ __forceinline__ u16 f2b(float f){ unsigned u=__builtin_bit_cast(unsigned,f); return (u16)((u+0x7fffu+((u>>16)&1u))>>16); }
__device__ __forceinline__ float wred(float v){
  #pragma unroll
  for(int off=32; off>0; off>>=1) v += __shfl_xor(v, off, 64);
  return v;
}
__device__ __forceinline__ void stOut(u16* p, float v){ *p = f2b(v); }
__device__ __forceinline__ void stOut(float* p, float v){ *p = v; }

// async global->LDS, 16B per lane: lane L writes ldsbase + L*16
__device__ __forceinline__ void gload_lds16(const void* g, void* l){
  __builtin_amdgcn_global_load_lds(
      (const __attribute__((address_space(1))) void*)g,
      (__attribute__((address_space(3))) void*)l, 16, 0, 0);
}

// reg-staged 8-elem store into LDS (fp32 source converted to bf16)
__device__ __forceinline__ void stageA8(u16* dst, const float* src){
  float4 a = *(const float4*)src;
  float4 b = *(const float4*)(src+4);
  ushort4 o0; o0.x=f2b(a.x); o0.y=f2b(a.y); o0.z=f2b(a.z); o0.w=f2b(a.w);
  ushort4 o1; o1.x=f2b(b.x); o1.y=f2b(b.y); o1.z=f2b(b.z); o1.w=f2b(b.w);
  *(ushort4*)dst = o0;
  *(ushort4*)(dst+4) = o1;
}

// ---------------- generic MFMA GEMM: C[M,N] = act(A[M,K] @ Wt^T + bias) ----------------
// A bf16 (global_load_lds staging) or fp32 (reg-staged + converted). Wt bf16 [n][k], row stride K.
// Tiles BM=128, BN=64, BK=64. LDS is LINEAR [r][64] with XOR swizzle: elem col ^= (r&7)<<3.
//   - global_load_lds dest is linear (wave-uniform base + lane*16); the SOURCE address carries
//     the inverse swizzle; ds_read applies the same XOR. (both-sides rule)
// MODE 0: +bias. MODE 1: relu(+bias). MODE 2: mult*sigmoid(+bias).
// DUAL: K split in half; first half reads A, second half reads A2 (both lda).
template<int MODE, typename OT, typename AT, bool DUAL>
__global__ __launch_bounds__(256) void gemm_k(
    const AT* __restrict__ A, const AT* __restrict__ A2, int lda,
    const u16* __restrict__ Wt, int K,
    const float* __restrict__ bias, int Nreal,
    OT* __restrict__ C, int ldc,
    const u16* __restrict__ mult, int ldm)
{
  __shared__ __align__(16) u16 As[128*64];
  __shared__ __align__(16) u16 Bs[64*64];
  const int tid = threadIdx.x;
  const size_t m0 = (size_t)blockIdx.x * 128;
  const int n0 = blockIdx.y * 64;
  const int lane = tid & 63, w = tid >> 6;
  const int lr = lane & 15, quad = lane >> 4;
  const int wr = (w >> 1) * 64, wc = (w & 1) * 32;
  const int swz = (lr & 7) << 3;
  const int KH = K >> 1;

  f32x4 acc[4][2];
  #pragma unroll
  for(int i=0;i<4;++i)
    #pragma unroll
    for(int j=0;j<2;++j) acc[i][j] = (f32x4){0.f,0.f,0.f,0.f};

  for(int k0=0; k0<K; k0+=64){
    const AT* Ap = A;
    int kcol = k0;
    if (DUAL && k0 >= KH) { Ap = A2; kcol = k0 - KH; }

    if constexpr (__is_same(AT, u16)) {
      // A tile 128x64 bf16 = 1024 x 16B chunks; each wave issues 4 global_load_lds
      #pragma unroll
      for(int it=0; it<4; ++it){
        int cbase = it*256 + w*64;
        int ch = cbase + lane;
        int r = ch >> 3;
        int ce = ((ch & 7) * 8) ^ ((r & 7) << 3);   // inverse-swizzled source col (elems)
        gload_lds16(Ap + (m0+r)*(size_t)lda + kcol + ce, &As[cbase*8]);
      }
    } else {
      // fp32 A: reg-stage + convert, write directly to swizzled LDS dest
      #pragma unroll
      for(int it=0; it<4; ++it){
        int ch = tid + 256*it; int r = ch>>3, s = (ch&7)*8;
        stageA8(&As[r*64 + (s ^ ((r&7)<<3))], Ap + (m0+r)*(size_t)lda + kcol + s);
      }
    }
    // W tile 64x64: 512 chunks; each wave issues 2 global_load_lds
    #pragma unroll
    for(int it=0; it<2; ++it){
      int cbase = it*256 + w*64;
      int ch = cbase + lane;
      int r = ch >> 3;
      int ce = ((ch & 7) * 8) ^ ((r & 7) << 3);
      gload_lds16(Wt + (size_t)(n0+r)*K + k0 + ce, &Bs[cbase*8]);
    }
    __syncthreads();
    #pragma unroll
    for(int kk=0; kk<64; kk+=32){
      bf16x8 af[4], bfr[2];
      #pragma unroll
      for(int i=0;i<4;++i)
        af[i]  = *(const bf16x8*)&As[(wr + i*16 + lr)*64 + ((kk + quad*8) ^ swz)];
      #pragma unroll
      for(int j=0;j<2;++j)
        bfr[j] = *(const bf16x8*)&Bs[(wc + j*16 + lr)*64 + ((kk + quad*8) ^ swz)];
      #pragma unroll
      for(int i=0;i<4;++i)
        #pragma unroll
        for(int j=0;j<2;++j)
          acc[i][j] = __builtin_amdgcn_mfma_f32_16x16x32_bf16(af[i], bfr[j], acc[i][j], 0, 0, 0);
    }
    __syncthreads();
  }
  // epilogue: D row = wr+i*16+quad*4+r, col = wc+j*16+lr
  #pragma unroll
  for(int j=0;j<2;++j){
    int col = n0 + wc + j*16 + lr;
    float bv = (col < Nreal) ? bias[col] : 0.f;
    #pragma unroll
    for(int i=0;i<4;++i){
      #pragma unroll
      for(int r=0;r<4;++r){
        size_t row = m0 + wr + i*16 + quad*4 + r;
        size_t ci = row*(size_t)ldc + col;
        float v = acc[i][j][r] + bv;
        if(MODE==1) v = fmaxf(v, 0.f);
        if(MODE==2){
          float mv = b2f(mult[row*(size_t)ldm + col]);
          v = mv * __builtin_amdgcn_rcpf(1.f + __expf(-v));
        }
        stOut(&C[ci], v);
      }
    }
  }
}

// ---------------- weight pre-transpose fp32->bf16 (+zero pad): dst[n*Kp+k] = src[k*N+n]
// one block per output row n: no integer division
struct TPar { const float* src; u16* dst; int K, N, Kp, Np; };
struct TArgs { TPar p[8]; };
__global__ __launch_bounds__(256) void transpose_all(TArgs args){
  TPar p = args.p[blockIdx.y];
  int n = blockIdx.x;
  if (n >= p.Np) return;
  for (int k = threadIdx.x; k < p.Kp; k += 256){
    u16 v = 0;
    if (n < p.N && k < p.K) v = f2b(p.src[(size_t)k*p.N + n]);
    p.dst[(size_t)n*p.Kp + k] = v;
  }
}

// ---------------- row-wise middle (weighted aliases eb, common aliases ep; same-row in-place)
__global__ __launch_bounds__(256) void mid_k(
    const u16* eb, const u16* ef, const u16* ep,
    const float* __restrict__ Wg, const float* __restrict__ bg,
    u16* common, u16* weighted)
{
  const int wid = threadIdx.x >> 6, lane = threadIdx.x & 63;
  const size_t row = (size_t)blockIdx.x * 4 + wid;
  const size_t base = row*256 + lane*4;

  ushort4 vb = *(const ushort4*)(eb + base);
  ushort4 vf = *(const ushort4*)(ef + base);
  ushort4 vp = *(const ushort4*)(ep + base);
  float fb[4] = {b2f(vb.x), b2f(vb.y), b2f(vb.z), b2f(vb.w)};
  float ff[4] = {b2f(vf.x), b2f(vf.y), b2f(vf.z), b2f(vf.w)};
  float fp[4] = {b2f(vp.x), b2f(vp.y), b2f(vp.z), b2f(vp.w)};

  float sb=0, sf=0, sp=0, d01=0, d02=0, d12=0, g0=0, g1=0, g2=0;
  #pragma unroll
  for(int j=0;j<4;++j){
    sb += fb[j]*fb[j]; sf += ff[j]*ff[j]; sp += fp[j]*fp[j];
    d01 += fb[j]*ff[j]; d02 += fb[j]*fp[j]; d12 += ff[j]*fp[j];
  }
  // weight generator: allc @ Wg, Wg is [768,3] fp32 row-major
  #pragma unroll
  for(int seg=0; seg<3; ++seg){
    const float* x = (seg==0) ? fb : (seg==1) ? ff : fp;
    const float* wg = Wg + ((size_t)seg*256 + lane*4)*3;
    float4 w0 = *(const float4*)(wg);
    float4 w1 = *(const float4*)(wg+4);
    float4 w2 = *(const float4*)(wg+8);
    float wv[12] = {w0.x,w0.y,w0.z,w0.w, w1.x,w1.y,w1.z,w1.w, w2.x,w2.y,w2.z,w2.w};
    #pragma unroll
    for(int j=0;j<4;++j){
      g0 += x[j]*wv[j*3+0];
      g1 += x[j]*wv[j*3+1];
      g2 += x[j]*wv[j*3+2];
    }
  }
  sb=wred(sb); sf=wred(sf); sp=wred(sp);
  d01=wred(d01); d02=wred(d02); d12=wred(d12);
  g0=wred(g0); g1=wred(g1); g2=wred(g2);

  // fast-math scalar tail: v_rsq / v_rcp / v_exp instead of libm div/sqrt/exp
  float inb  = __builtin_amdgcn_rsqf(fmaxf(sb, 1e-24f));   // == 1/max(sqrt(sb),1e-12)
  float invf = __builtin_amdgcn_rsqf(fmaxf(sf, 1e-24f));
  float inp  = __builtin_amdgcn_rsqf(fmaxf(sp, 1e-24f));
  float s01 = d01*inb*invf, s02 = d02*inb*inp, s12 = d12*invf*inp;

  g0 += bg[0]; g1 += bg[1]; g2 += bg[2];
  float gm = fmaxf(g0, fmaxf(g1, g2));
  float e0 = __expf(g0-gm), e1 = __expf(g1-gm), e2 = __expf(g2-gm);
  float res = __builtin_amdgcn_rcpf(e0+e1+e2);
  float fw0 = e0*res, fw1 = e1*res, fw2 = e2*res;

  bool p0 = s01 > 0.6f, p1 = s02 > 0.6f, p2 = s12 > 0.6f;
  bool has = p0 || p1 || p2;
  float mm = -__builtin_inff();
  if(p0) mm = fmaxf(mm, s01);
  if(p1) mm = fmaxf(mm, s02);
  if(p2) mm = fmaxf(mm, s12);
  if(!has) mm = 0.f;
  float q0 = p0 ? __expf(s01-mm) : 0.f;
  float q1 = p1 ? __expf(s02-mm) : 0.f;
  float q2 = p2 ? __expf(s12-mm) : 0.f;
  float rqs = __builtin_amdgcn_rcpf(fmaxf(q0+q1+q2, 1e-12f));
  float w0 = q0*rqs, w1 = q1*rqs, w2 = q2*rqs;

  u16 co[4], wt[4];
  #pragma unroll
  for(int j=0;j<4;++j){
    float a = fb[j], b = ff[j], c = fp[j];
    float na = a*inb, nbv = b*invf, nc = c*inp;
    float c0 = (na*nbv > 0.6f) ? 0.5f*(a+b) : 0.f;
    float c1 = (na*nc  > 0.6f) ? 0.5f*(a+c) : 0.f;
    float c2 = (nbv*nc > 0.6f) ? 0.5f*(b+c) : 0.f;
    float sc = c0*w0 + c1*w1 + c2*w2;
    float cf = has ? sc : (a+b+c)*(1.f/3.f);
    float wv = a*fw0 + b*fw1 + c*fw2;
    co[j] = f2b(cf); wt[j] = f2b(wv);
  }
  ushort4 oc, ow;
  oc.x=co[0]; oc.y=co[1]; oc.z=co[2]; oc.w=co[3];
  ow.x=wt[0]; ow.y=wt[1]; ow.z=wt[2]; ow.w=wt[3];
  *(ushort4*)(common + base) = oc;     // in-place over ep
  *(ushort4*)(weighted + base) = ow;   // in-place over eb
}

extern "C" void kernel_launch(void* const* d_in, const int* in_sizes, int n_in,
                              void* d_out, int out_size, void* d_ws, size_t ws_size,
                              hipStream_t stream) {
  const float* brics = (const float*)d_in[0];
  const float* fg    = (const float*)d_in[1];
  const float* ph    = (const float*)d_in[2];
  const float* W1[3] = {(const float*)d_in[3], (const float*)d_in[7], (const float*)d_in[11]};
  const float* b1[3] = {(const float*)d_in[4], (const float*)d_in[8], (const float*)d_in[12]};
  const float* W2[3] = {(const float*)d_in[5], (const float*)d_in[9], (const float*)d_in[13]};
  const float* b2[3] = {(const float*)d_in[6], (const float*)d_in[10], (const float*)d_in[14]};
  const float* Wg = (const float*)d_in[15];
  const float* bg = (const float*)d_in[16];
  const float* We = (const float*)d_in[17];
  const float* be = (const float*)d_in[18];
  const float* Wf = (const float*)d_in[19];
  const float* bf = (const float*)d_in[20];
  float* out = (float*)d_out;

  const int M = in_sizes[0] / 256;   // 65536

  // ---- workspace carve ----
  char* wsp = (char*)d_ws;
  size_t off = 0;
  auto carve = [&](size_t elems)->u16* {
    u16* p = (u16*)(wsp + off);
    off += ((elems*sizeof(u16)) + 255) & ~(size_t)255;
    return p;
  };
  u16* xb0 = carve((size_t)M*256);   // enc0 (brics), then weighted (in-place)
  u16* xb1 = carve((size_t)M*256);   // enc1 (fg), then ce (gate out)
  u16* xb2 = carve((size_t)M*256);   // enc2 (ph), then common (in-place)
  u16* h   = carve((size_t)M*320);   // encoder hidden
  u16* Wt1[3], *Wt2[3];
  for(int i=0;i<3;++i) Wt1[i] = carve(320*256);
  for(int i=0;i<3;++i) Wt2[i] = carve(256*320);
  u16* WtE = carve(256*256);
  u16* WtF = carve(256*512);         // full fused-output weight: [n=256][k=512]
  (void)ws_size; (void)n_in; (void)out_size;

  // ---- 1. transpose/convert all weights (activation convert is fused into GEMM1 staging) ----
  TArgs ta;
  for(int i=0;i<3;++i){
    ta.p[i]   = {W1[i], Wt1[i], 256, 300, 256, 320};  // Wt1: [320][256]
    ta.p[3+i] = {W2[i], Wt2[i], 300, 256, 320, 256};  // Wt2: [256][320]
  }
  ta.p[6] = {We, WtE, 256, 256, 256, 256};
  ta.p[7] = {Wf, WtF, 512, 256, 512, 256};            // Wf: [512,256] -> WtF [256][512]
  transpose_all<<<dim3(512, 8), 256, 0, stream>>>(ta);

  // ---- 2. encoders: h = relu(x_fp32@W1+b1); enc[i] = h@W2+b2 ----
  const float* xin[3] = {brics, fg, ph};
  u16* encp[3] = {xb0, xb1, xb2};
  for(int i=0;i<3;++i){
    gemm_k<1,u16,float,false><<<dim3(M/128, 5), 256, 0, stream>>>(
        xin[i], nullptr, 256, Wt1[i], 256, b1[i], 300, h, 320, nullptr, 0);
    gemm_k<0,u16,u16,false><<<dim3(M/128, 4), 256, 0, stream>>>(
        h, nullptr, 320, Wt2[i], 320, b2[i], 256, encp[i], 256, nullptr, 0);
  }

  // ---- 3. row-wise middle: weighted -> xb0 (in place), common -> xb2 (in place) ----
  mid_k<<<M/4, 256, 0, stream>>>(xb0, xb1, xb2, Wg, bg, /*common=*/xb2, /*weighted=*/xb0);

  // ---- 4. gate: ce(xb1) = common * sigmoid(common@We + be) ----
  gemm_k<2,u16,u16,false><<<dim3(M/128, 4), 256, 0, stream>>>(
      xb2, nullptr, 256, WtE, 256, be, 256, xb1, 256, xb2, 256);

  // ---- 5. fused output: out = [weighted | ce] @ WtF^T + bf  (single K=512 GEMM) ----
  gemm_k<0,float,u16,true><<<dim3(M/128, 4), 256, 0, stream>>>(
      xb0, xb1, 256, WtF, 512, bf, 256, out, 256, nullptr, 0);
}